// Round 5
// baseline (455.547 us; speedup 1.0000x reference)
//
#include <hip/hip_runtime.h>
#include <math.h>

#define D 128
#define MTILE 32
#define MAXCH 1280

// ---- workspace layout (int words) ----
#define W_NCH   0
#define W_CNT_E 16                  // 128
#define W_CNT_R 144                 // 64
#define W_RUN_E 208                 // 128  (scatter running offsets)
#define W_RUN_R 336                 // 64
#define W_CHP0  512                 // [MAXCH]
#define W_CHN   (512 + MAXCH)       // [MAXCH]
#define W_CHTT  (512 + 2 * MAXCH)   // [MAXCH] (type | side<<8)
#define W_SRT   8192                // srt_e[B], inv_e[B], srt_r[B], inv_r[B]
// Ye float offset = 8192 + 4*B ; Yr = Ye + B*128

__global__ __launch_bounds__(256) void zero_kernel(int* ws) {
    int tid = threadIdx.x;
    if (tid < 192) ws[W_CNT_E + tid] = 0;   // cnt_e[128] + cnt_r[64] (contiguous)
}

__global__ __launch_bounds__(256) void count_kernel(
    const int* __restrict__ etypes, const int* __restrict__ rtypes,
    int* __restrict__ ws, int B)
{
    int b = blockIdx.x * blockDim.x + threadIdx.x;
    if (b < B) {
        atomicAdd(&ws[W_CNT_E + etypes[b]], 1);
        atomicAdd(&ws[W_CNT_R + rtypes[b]], 1);
    }
}

// 1 block, 256 threads: per-side row-offset scans + combined chunk scan +
// cooperative descriptor fill (binary search over chunk-start prefix).
__global__ __launch_bounds__(256) void scan_build_kernel(int* __restrict__ ws) {
    __shared__ int s_cnt[192];   // slot: 0..127 = e-type, 128..191 = r-type
    __shared__ int s_off[192];   // within-side row start
    __shared__ int s_cs[193];    // combined chunk-start prefix (exclusive)
    __shared__ int tmp[256];
    const int tid = threadIdx.x;

    // load counts
    if (tid < 192) s_cnt[tid] = ws[W_CNT_E + tid];   // contiguous cnt_e|cnt_r
    __syncthreads();

    // ---- entity row-offset scan (slots 0..127) ----
    int c = (tid < 128) ? s_cnt[tid] : 0;
    if (tid < 128) tmp[tid] = c;
    __syncthreads();
    for (int off = 1; off < 128; off <<= 1) {
        int v = (tid < 128 && tid >= off) ? tmp[tid - off] : 0;
        __syncthreads();
        if (tid < 128) tmp[tid] += v;
        __syncthreads();
    }
    if (tid < 128) s_off[tid] = tmp[tid] - c;
    __syncthreads();

    // ---- relation row-offset scan (slots 128..191) ----
    c = (tid < 64) ? s_cnt[128 + tid] : 0;
    if (tid < 64) tmp[tid] = c;
    __syncthreads();
    for (int off = 1; off < 64; off <<= 1) {
        int v = (tid < 64 && tid >= off) ? tmp[tid - off] : 0;
        __syncthreads();
        if (tid < 64) tmp[tid] += v;
        __syncthreads();
    }
    if (tid < 64) s_off[128 + tid] = tmp[tid] - c;
    __syncthreads();

    // ---- combined chunk-count scan over 192 slots ----
    int nch = (tid < 192) ? ((s_cnt[tid] + MTILE - 1) / MTILE) : 0;
    tmp[tid] = nch;
    __syncthreads();
    for (int off = 1; off < 256; off <<= 1) {
        int v = (tid >= off) ? tmp[tid - off] : 0;
        __syncthreads();
        tmp[tid] += v;
        __syncthreads();
    }
    if (tid < 192) s_cs[tid] = tmp[tid] - nch;
    if (tid == 191) { s_cs[192] = tmp[191]; ws[W_NCH] = tmp[191]; }
    __syncthreads();

    // publish scatter start offsets
    if (tid < 192) ws[W_RUN_E + tid] = s_off[tid];   // RUN_E|RUN_R contiguous

    // ---- cooperative descriptor fill ----
    const int total = s_cs[192];
    for (int ci = tid; ci < total; ci += 256) {
        int lo = 0, hi = 192;
        while (hi - lo > 1) {
            int mid = (lo + hi) >> 1;
            if (s_cs[mid] <= ci) lo = mid; else hi = mid;
        }
        int q = ci - s_cs[lo];
        int side = lo >> 7;
        int type = lo & 127;          // 0..63 for relation slots
        int rem = s_cnt[lo] - q * MTILE;
        ws[W_CHP0 + ci] = s_off[lo] + q * MTILE;
        ws[W_CHN  + ci] = rem < MTILE ? rem : MTILE;
        ws[W_CHTT + ci] = type | (side << 8);
    }
}

__global__ __launch_bounds__(256) void scatter_kernel(
    const int* __restrict__ etypes, const int* __restrict__ rtypes,
    int* __restrict__ ws, int B)
{
    int* srt_e = ws + W_SRT;
    int* inv_e = srt_e + B;
    int* srt_r = inv_e + B;
    int* inv_r = srt_r + B;
    int b = blockIdx.x * blockDim.x + threadIdx.x;
    if (b < B) {
        int pe = atomicAdd(&ws[W_RUN_E + etypes[b]], 1);
        srt_e[pe] = b; inv_e[b] = pe;
        int pr = atomicAdd(&ws[W_RUN_R + rtypes[b]], 1);
        srt_r[pr] = b; inv_r[b] = pr;
    }
}

// One chunk (32 rows x full N=128) per block. side 0: X=h-t, out->Ye.
// side 1: X=remb[rel], out->Yr. Pure "=" stores, no ordering needed.
__global__ __launch_bounds__(256) void gemm_fused(
    const int* __restrict__ heads, const int* __restrict__ tails,
    const int* __restrict__ rels,
    const float* __restrict__ eemb, const float* __restrict__ remb,
    const float* __restrict__ eproj, const float* __restrict__ rproj,
    const int* __restrict__ ws, int B,
    float* __restrict__ Ye, float* __restrict__ Yr)
{
    const int nch = ws[W_NCH];
    if ((int)blockIdx.x >= nch) return;
    const int p0  = ws[W_CHP0 + blockIdx.x];
    const int nr  = ws[W_CHN  + blockIdx.x];
    const int tts = ws[W_CHTT + blockIdx.x];
    const int side = tts >> 8, tt = tts & 255;
    const int* srt = ws + W_SRT + (side ? 2 * B : 0);
    const float* P = (side ? rproj : eproj) + (size_t)tt * D * D;
    float* Y = side ? Yr : Ye;

    __shared__ float Xs[MTILE * 132];   // stride 132 floats (pad 4)
    __shared__ float Ps[D * 36];        // stride 36 floats (pad 4)

    const int tid = threadIdx.x;

    // stage X tile (full K=128), gather fused
    for (int idx = tid; idx < MTILE * 32; idx += 256) {
        int row = idx >> 5, kq = idx & 31;
        float4 v = {0.f, 0.f, 0.f, 0.f};
        if (row < nr) {
            int b = srt[p0 + row];
            if (side == 0) {
                float4 hv = ((const float4*)(eemb + (size_t)heads[b] * D))[kq];
                float4 tv = ((const float4*)(eemb + (size_t)tails[b] * D))[kq];
                v.x = hv.x - tv.x; v.y = hv.y - tv.y;
                v.z = hv.z - tv.z; v.w = hv.w - tv.w;
            } else {
                v = ((const float4*)(remb + (size_t)rels[b] * D))[kq];
            }
        }
        *(float4*)&Xs[row * 132 + kq * 4] = v;
    }

    float acc[2][8];
    #pragma unroll
    for (int j = 0; j < 2; ++j)
        #pragma unroll
        for (int i = 0; i < 8; ++i) acc[j][i] = 0.f;

    const int ty = tid >> 4, tx = tid & 15;   // rows ty*2+{0,1}, cols i*16+tx

    for (int k0 = 0; k0 < 32; k0 += 8) {      // k in float4-quads
        __syncthreads();
        for (int idx = tid; idx < 1024; idx += 256) {
            int n = idx >> 3, kq = idx & 7;
            float4 v = *(const float4*)&P[(size_t)n * D + (k0 + kq) * 4];
            *(float4*)&Ps[n * 36 + kq * 4] = v;
        }
        __syncthreads();

        #pragma unroll
        for (int kq = 0; kq < 8; ++kq) {
            float4 xv[2], pv[8];
            #pragma unroll
            for (int j = 0; j < 2; ++j)
                xv[j] = *(const float4*)&Xs[(ty * 2 + j) * 132 + (k0 + kq) * 4];
            #pragma unroll
            for (int i = 0; i < 8; ++i)
                pv[i] = *(const float4*)&Ps[(i * 16 + tx) * 36 + kq * 4];
            #pragma unroll
            for (int j = 0; j < 2; ++j)
                #pragma unroll
                for (int i = 0; i < 8; ++i)
                    acc[j][i] += xv[j].x * pv[i].x + xv[j].y * pv[i].y
                               + xv[j].z * pv[i].z + xv[j].w * pv[i].w;
        }
    }

    #pragma unroll
    for (int j = 0; j < 2; ++j) {
        int m = ty * 2 + j;
        if (m < nr) {
            float* yp = Y + (size_t)(p0 + m) * D + tx;
            #pragma unroll
            for (int i = 0; i < 8; ++i) yp[i * 16] = acc[j][i];
        }
    }
}

__global__ __launch_bounds__(256) void norm_kernel(
    const int* __restrict__ ws, int B,
    const float* __restrict__ Ye, const float* __restrict__ Yr,
    float* __restrict__ out)
{
    int wave = threadIdx.x >> 6, lane = threadIdx.x & 63;
    int gb = blockIdx.x * 4 + wave;
    if (gb >= B) return;
    int re = ws[W_SRT + B + gb];          // inv_e[gb]
    int rr = ws[W_SRT + 3 * B + gb];      // inv_r[gb]
    float2 a = ((const float2*)(Ye + (size_t)re * D))[lane];
    float2 c = ((const float2*)(Yr + (size_t)rr * D))[lane];
    float x0 = a.x + c.x, x1 = a.y + c.y;
    float ss = x0 * x0 + x1 * x1;
    #pragma unroll
    for (int off = 32; off > 0; off >>= 1)
        ss += __shfl_down(ss, off, 64);
    if (lane == 0) out[gb] = sqrtf(ss);
}

extern "C" void kernel_launch(void* const* d_in, const int* in_sizes, int n_in,
                              void* d_out, int out_size, void* d_ws, size_t ws_size,
                              hipStream_t stream) {
    const int*   heads     = (const int*)d_in[0];
    const int*   relations = (const int*)d_in[1];
    const int*   tails     = (const int*)d_in[2];
    const int*   etypes    = (const int*)d_in[3];
    const int*   rtypes    = (const int*)d_in[4];
    const float* eemb      = (const float*)d_in[5];
    const float* remb      = (const float*)d_in[6];
    const float* eproj     = (const float*)d_in[7];
    const float* rproj     = (const float*)d_in[8];
    float* out = (float*)d_out;

    const int B = in_sizes[0];   // 16384
    int* ws = (int*)d_ws;
    float* Ye = (float*)d_ws + (W_SRT + 4 * B);
    float* Yr = Ye + (size_t)B * D;

    zero_kernel<<<1, 256, 0, stream>>>(ws);
    count_kernel<<<(B + 255) / 256, 256, 0, stream>>>(etypes, rtypes, ws, B);
    scan_build_kernel<<<1, 256, 0, stream>>>(ws);
    scatter_kernel<<<(B + 255) / 256, 256, 0, stream>>>(etypes, rtypes, ws, B);
    gemm_fused<<<MAXCH, 256, 0, stream>>>(heads, tails, relations,
                                          eemb, remb, eproj, rproj, ws, B, Ye, Yr);
    norm_kernel<<<(B + 3) / 4, 256, 0, stream>>>(ws, B, Ye, Yr, out);
}